// Round 17
// baseline (1959.338 us; speedup 1.0000x reference)
//
#include <hip/hip_runtime.h>

// LSTM B=1024, T=256, H=256, fp32-accurate via bf16x2-split (3-term) MFMA. v17.
// = v16 (one kernel per timestep; HW dispatch ordering replaces all in-kernel
// cross-block sync) with exec-path fat removed:
//  1. h is exchanged in PRE-SPLIT fragment-order planes. Block (rg,cg)'s
//     32 output hcols are exactly the ks=cg slice of the consumer frag layout
//     -> producer repacks via LDS (coalesced 16B stores), consumer staging is
//     a linear 32KB copy with ZERO unpack VALU.
//  2. x pre-transposed to xT[t][row] (prep) -> 32 contiguous floats per
//     block-step instead of 4096 stride-1KB scalar loads.
//  3. prep fused (weight split + x transpose); head reads split planes.
//
// Step kernel: grid 256 = 32 rowgroups (32 rows) x 8 colgroups (32 hcols);
// cg = bid&7 so same-XCD blocks share one 128KB weight slice in L2 (perf
// only). Block 512 thr = 8 waves; wave = full K=256 for 16 gatecols x 2 row
// halves via 16x16x32 MFMA (A row=lane&15, k=ks*32+(lane>>4)*8+e;
// D col=lane&15, row=(lane>>4)*4+reg). Weights pre-split in frag order ->
// 16 coalesced dwordx4/thread. Reference bias swap preserved (f<-b_o, o<-b_f).
//
// Split-plane global layout, per rowgroup rg (32KB block):
//   off = rg*32768 + half*16384 + plane*8192 + ks*1024 + lane*16 + e*2
//   holds split[plane] of h[row = half*16 + (lane&15)][k = ks*32+(lane>>4)*8+e]

#define Bsz   1024
#define Tt    256
#define Hh    256
#define NCLS  10
#define NTHR  512
#define WSPN  32768                   // s16x8 frags per split plane

typedef float f32x4 __attribute__((ext_vector_type(4)));
typedef short s16x8 __attribute__((ext_vector_type(8)));
typedef unsigned int u32;

__device__ __forceinline__ unsigned short f2bf(float f) {   // RNE f32->bf16
    u32 u = __builtin_bit_cast(u32, f);
    return (unsigned short)((u + 0x7FFFu + ((u >> 16) & 1u)) >> 16);
}
__device__ __forceinline__ float bf2f(unsigned short b) {
    u32 u = ((u32)b) << 16;
    return __builtin_bit_cast(float, u);
}
template<int CTRL>
__device__ __forceinline__ float quadf(float v) {           // quad_perm bcast
    return __builtin_bit_cast(float,
        __builtin_amdgcn_update_dpp(0, __builtin_bit_cast(int, v),
                                    CTRL, 0xF, 0xF, true));
}
__device__ __forceinline__ float fast_tanh(float v) {
    const float e = __expf(-2.0f * fabsf(v));
    const float t = (1.0f - e) * __builtin_amdgcn_rcpf(1.0f + e);
    return copysignf(t, v);
}

// ---- prep (once): split weights into frag order + transpose x ----
extern "C" __global__ void __launch_bounds__(256)
lstm_prep(const float* __restrict__ W_gh, const float* __restrict__ W_ih,
          const float* __restrict__ W_fh, const float* __restrict__ W_oh,
          const float* __restrict__ x,
          short* __restrict__ wsp, float* __restrict__ xT)
{
    const int bid = blockIdx.x;
    if (bid < 128) {                    // weight split: 32768 frag-threads
        const int idx  = bid * 256 + threadIdx.x;   // ((cg*8+wv)*8+ks)*64+lane
        const int lane = idx & 63;
        const int ks   = (idx >> 6) & 7;
        const int wv   = (idx >> 9) & 7;
        const int cg   = idx >> 12;
        const int gate = lane & 3;
        const int hcol_g = cg * 32 + wv * 4 + ((lane & 15) >> 2);
        const int krow = lane >> 4;
        const float* __restrict__ Wg =
            (gate == 0) ? W_gh : (gate == 1) ? W_ih : (gate == 2) ? W_fh : W_oh;
        s16x8 v1, v2;
        #pragma unroll
        for (int e = 0; e < 8; ++e) {
            const float w = Wg[(size_t)(ks * 32 + krow * 8 + e) * Hh + hcol_g];
            const unsigned short c1 = f2bf(w);
            const unsigned short c2 = f2bf(w - bf2f(c1));
            v1[e] = (short)c1; v2[e] = (short)c2;
        }
        *(s16x8*)(wsp + (size_t)idx * 8)          = v1;
        *(s16x8*)(wsp + (size_t)(WSPN + idx) * 8) = v2;
    } else {                            // x transpose: xT[t*1024+row]
        const int idx = (bid - 128) * 256 + threadIdx.x;    // 262144
        const int t   = idx >> 10;
        const int row = idx & 1023;
        xT[(size_t)t * Bsz + row] = x[(size_t)row * Tt + t];
    }
}

// ---- one timestep: hsplit(t) -> hsplit(t+1), c in place ----
extern "C" __global__ void __launch_bounds__(NTHR, 2)
lstm_step(const float* __restrict__ xT,
          const float* __restrict__ W_gx, const float* __restrict__ b_g,
          const float* __restrict__ W_ix, const float* __restrict__ b_i,
          const float* __restrict__ W_fx, const float* __restrict__ b_f,
          const float* __restrict__ W_ox, const float* __restrict__ b_o,
          const short* __restrict__ wsp,
          const char* __restrict__ hcur, char* __restrict__ hnxt,
          float* __restrict__ cst, int t)
{
    __shared__ __align__(16) char smem[32768];   // frag-order planes (copy of rg block)
    __shared__ u32   hown[32 * 33];              // packed (lo|hi<<16) outputs
    __shared__ float xsh[32];

    const int tid  = threadIdx.x;
    const int lane = tid & 63;
    const int wv   = tid >> 6;
    const int cg   = blockIdx.x & 7;
    const int rg   = blockIdx.x >> 3;
    const int r0   = rg * 32;

    const int gate   = lane & 3;
    const int hcol_l = wv * 4 + ((lane & 15) >> 2);
    const int hcol_g = cg * 32 + hcol_l;
    const int krow   = lane >> 4;

    // ---- weights: 16 coalesced dwordx4 frag loads, no VALU ----
    const s16x8* __restrict__ W1 =
        (const s16x8*)wsp + ((size_t)(cg * 8 + wv) * 8 * 64 + lane);
    s16x8 bw1[8], bw2[8];
    #pragma unroll
    for (int ks = 0; ks < 8; ++ks) {
        bw1[ks] = W1[ks * 64];
        bw2[ks] = W1[WSPN + ks * 64];
    }

    const float wx = ((gate == 0) ? W_gx : (gate == 1) ? W_ix : (gate == 2) ? W_fx : W_ox)[hcol_g];
    const float bb = ((gate == 0) ? b_g  : (gate == 1) ? b_i  : (gate == 2) ? b_o  : b_f )[hcol_g];

    // c loads (hoisted; independent of staging)
    float cold[2][4];
    #pragma unroll
    for (int half = 0; half < 2; ++half)
        #pragma unroll
        for (int r = 0; r < 4; ++r)
            cold[half][r] = cst[(size_t)(r0 + half * 16 + krow * 4 + r) * Hh + hcol_g];

    // x stage: 32 contiguous floats
    if (tid < 32) xsh[tid] = xT[(size_t)t * Bsz + r0 + tid];

    // ---- stage h(t): linear 32KB copy, zero unpack ----
    {
        const char* src = hcur + (size_t)rg * 32768;
        #pragma unroll
        for (int i = 0; i < 4; ++i) {
            const int off = (tid + i * NTHR) * 16;
            *(uint4*)(smem + off) = *(const uint4*)(src + off);
        }
    }
    __syncthreads();

    // ---- per half: 24 MFMA (3 indep chains) + phase B ----
    #pragma unroll
    for (int half = 0; half < 2; ++half) {
        f32x4 aA = {0.f,0.f,0.f,0.f}, aB = {0.f,0.f,0.f,0.f}, aC = {0.f,0.f,0.f,0.f};
        #pragma unroll
        for (int ks = 0; ks < 8; ++ks) {
            const char* ab = smem + half * 16384 + ks * 1024 + lane * 16;
            const s16x8 a1 = *(const s16x8*)ab;
            const s16x8 a2 = *(const s16x8*)(ab + 8192);
            aA = __builtin_amdgcn_mfma_f32_16x16x32_bf16(a1, bw1[ks], aA, 0, 0, 0);
            aB = __builtin_amdgcn_mfma_f32_16x16x32_bf16(a2, bw1[ks], aB, 0, 0, 0);
            aC = __builtin_amdgcn_mfma_f32_16x16x32_bf16(a1, bw2[ks], aC, 0, 0, 0);
        }
        const f32x4 acc = aA + aB + aC;

        #pragma unroll
        for (int r = 0; r < 4; ++r) {
            const int rowl = half * 16 + krow * 4 + r;
            const float pre = acc[r] + fmaf(xsh[rowl], wx, bb);
            const float vin = (gate == 0) ? 2.0f * pre : pre;
            const float e   = __expf(-fabsf(vin));
            const float rc  = __builtin_amdgcn_rcpf(1.0f + e);
            const float sig = (vin >= 0.0f) ? rc : 1.0f - rc;
            const float th  = copysignf((1.0f - e) * rc, pre);
            const float act = (gate == 0) ? th : sig;
            const float gv = quadf<0x00>(act);
            const float iv = quadf<0x55>(act);
            const float fv = quadf<0xAA>(act);
            const float ov = quadf<0xFF>(act);
            const float cnew = fmaf(gv, iv, cold[half][r] * fv);
            const float hv   = fast_tanh(cnew) * ov;
            if (gate == 0) {
                cst[(size_t)(r0 + rowl) * Hh + hcol_g] = cnew;
                const unsigned short h1 = f2bf(hv);
                const unsigned short h2 = f2bf(hv - bf2f(h1));
                hown[rowl * 33 + hcol_l] = (u32)h1 | ((u32)h2 << 16);
            }
        }
    }
    __syncthreads();

    // ---- repack own 1024 values -> ks=cg slice of hnxt (coalesced 16B) ----
    if (tid < 256) {
        const int half  = tid >> 7;
        const int plane = (tid >> 6) & 1;
        const int l     = tid & 63;
        const int rowl  = half * 16 + (l & 15);
        u32 w4[4];
        #pragma unroll
        for (int j = 0; j < 4; ++j) {
            const u32 pa = hown[rowl * 33 + (l >> 4) * 8 + 2 * j];
            const u32 pb = hown[rowl * 33 + (l >> 4) * 8 + 2 * j + 1];
            const u32 va = plane ? (pa >> 16) : (pa & 0xffffu);
            const u32 vb = plane ? (pb >> 16) : (pb & 0xffffu);
            w4[j] = va | (vb << 16);
        }
        *(uint4*)(hnxt + (size_t)rg * 32768 + half * 16384 + plane * 8192
                       + cg * 1024 + l * 16) = *(uint4*)w4;
    }
}

// ---- head: out = h_T @ W_ph + b_p, reconstructing h from split planes ----
extern "C" __global__ void __launch_bounds__(256)
lstm_head(const char* __restrict__ hT, const float* __restrict__ W_ph,
          const float* __restrict__ b_p, float* __restrict__ out)
{
    __shared__ __align__(16) char tile[32768];
    const int tid = threadIdx.x;
    const int rg  = blockIdx.x;
    const char* src = hT + (size_t)rg * 32768;
    for (int i = tid; i < 2048; i += 256)
        *(uint4*)(tile + i * 16) = *(const uint4*)(src + i * 16);
    __syncthreads();
    for (int idx = tid; idx < 32 * NCLS; idx += 256) {
        const int rowl = idx / NCLS;
        const int cc   = idx - rowl * NCLS;
        const int half = rowl >> 4;
        const int l4   = rowl & 15;
        float a = b_p[cc];
        for (int k = 0; k < Hh; ++k) {
            const int lane = ((k >> 3) & 3) * 16 + l4;
            const int off  = half * 16384 + (k >> 5) * 1024 + lane * 16 + (k & 7) * 2;
            const unsigned short lo = *(const unsigned short*)(tile + off);
            const unsigned short hi = *(const unsigned short*)(tile + off + 8192);
            a = fmaf(bf2f(lo) + bf2f(hi), W_ph[k * NCLS + cc], a);
        }
        out[(size_t)(rg * 32 + rowl) * NCLS + cc] = a;
    }
}

extern "C" void kernel_launch(void* const* d_in, const int* in_sizes, int n_in,
                              void* d_out, int out_size, void* d_ws, size_t ws_size,
                              hipStream_t stream) {
    const float* x    = (const float*)d_in[0];
    const float* W_gx = (const float*)d_in[1];
    const float* W_gh = (const float*)d_in[2];
    const float* b_g  = (const float*)d_in[3];
    const float* W_ix = (const float*)d_in[4];
    const float* W_ih = (const float*)d_in[5];
    const float* b_i  = (const float*)d_in[6];
    const float* W_fx = (const float*)d_in[7];
    const float* W_fh = (const float*)d_in[8];
    const float* b_f  = (const float*)d_in[9];
    const float* W_ox = (const float*)d_in[10];
    const float* W_oh = (const float*)d_in[11];
    const float* b_o  = (const float*)d_in[12];
    const float* W_ph = (const float*)d_in[13];
    const float* b_p  = (const float*)d_in[14];
    float* out = (float*)d_out;

    // d_ws: hsplit0 1MB | hsplit1 1MB | c 1MB | wsp 1MB | xT 1MB  (5MB... no:
    // hsplit buffers are 32rg x 32KB = 1MB each; xT = 1024*256*4B = 1MB)
    char*  hs0 = (char*)d_ws;
    char*  hs1 = (char*)d_ws + (1u << 20);
    float* cst = (float*)((char*)d_ws + (2u << 20));
    short* wsp = (short*)((char*)d_ws + (3u << 20));
    float* xT  = (float*)((char*)d_ws + (3u << 20) + (1u << 20));

    // zero h(0) split planes (split of 0 is 0) and c
    hipMemsetAsync(d_ws, 0, 3u << 20, stream);

    lstm_prep<<<dim3(128 + 1024), dim3(256), 0, stream>>>(
        W_gh, W_ih, W_fh, W_oh, x, wsp, xT);

    for (int t = 0; t < Tt; ++t) {
        const char* hcur = (t & 1) ? hs1 : hs0;
        char*       hnxt = (t & 1) ? hs0 : hs1;
        lstm_step<<<dim3(256), dim3(NTHR), 0, stream>>>(
            xT, W_gx, b_g, W_ix, b_i, W_fx, b_f, W_ox, b_o,
            wsp, hcur, hnxt, cst, t);
    }

    // h(256) in buffer 0
    lstm_head<<<dim3(32), dim3(256), 0, stream>>>(hs0, W_ph, b_p, out);
}